// Round 20
// baseline (207.738 us; speedup 1.0000x reference)
//
#include <hip/hip_runtime.h>
#include <hip/hip_bf16.h>

#define HH 1024
#define WW 1024
#define CC 8
#define LL 8
#define RAD 25
#define EPSV 1e-6f
#define SEG 16              // rows per vertical prefix segment
#define NSEG (HH / SEG)     // 64
#define NPL 72              // 64 joint planes + 8 oc planes
#define NTASK (NSEG * CC * 9)   // 4608 wave-tasks
#define NBLK  (NTASK / 2)       // 2304 blocks (2 waves each)
#define BPX   (NBLK / 8)        // 288 blocks per XCD chunk

typedef unsigned short u16;
typedef unsigned int   u32;
typedef u32   u32x4 __attribute__((ext_vector_type(4)));
typedef float f32x4 __attribute__((ext_vector_type(4)));

__device__ __forceinline__ u16 bf16r(float x) {
    u32 b = __float_as_uint(x);
    b += 0x7FFFu + ((b >> 16) & 1u);     // round-to-nearest-even
    return (u16)(b >> 16);
}

// 16B-granule XOR swizzle (R18: conflicts 18.4M -> 3.4M).
__device__ __forceinline__ int swz(int g) { return g ^ ((g >> 3) & 7); }

// =====================================================================
// K1: per-row horizontal 51-window sums, one WAVE per (segment, c, plane)
// task; rows in PAIRS. LDS float layout: [32 zeros][1024 prefix][32 total]
// stored as XOR-swizzled 16B granules. Barriers at write->read
// boundaries (R15 inf bug).
// =====================================================================
__global__ __launch_bounds__(128) void hprefix8(const float* __restrict__ ca,
                                                const float* __restrict__ nn,
                                                u16* __restrict__ PH,
                                                float* __restrict__ SegT) {
    const int t    = threadIdx.x;
    const int lane = t & 63;
    const int w    = t >> 6;               // wave in block 0..1
    const int blk  = blockIdx.x;           // 0..2303
    const int task = ((blk & 7) * BPX + (blk >> 3)) * 2 + w;   // 0..4607
    const int yseg = task / (CC * 9);
    const int rem  = task - yseg * (CC * 9);
    const int c    = rem / 9;
    const int p    = rem - c * 9;          // 0..7 joint, 8 = oc plane

    __shared__ __align__(16) float Pbuf[2][2][1088];
    float* __restrict__ lp0 = Pbuf[w][0];
    float* __restrict__ lp1 = Pbuf[w][1];

    const int pl = (p < 8) ? (c * 8 + p) : (64 + c);
    const float* carow = ca + (size_t)c * HH * WW + 16 * lane;
    const float* nnrow = nn + (size_t)(p < 8 ? p : 0) * HH * WW + 16 * lane;
    const int x0 = 16 * lane;

    // precomputed swizzled float offsets (loop-invariant)
    int wg[4], hg[5], lg[5];
    #pragma unroll
    for (int k = 0; k < 4; ++k) wg[k] = 4 * swz(8 + 4 * lane + k);
    #pragma unroll
    for (int k = 0; k < 5; ++k) {
        hg[k] = 4 * swz(14 + 4 * lane + k);
        lg[k] = 4 * swz(1 + 4 * lane + k);
    }

    // zero head (granules 0..7 are identity under swz)
    if (lane < 32) { lp0[lane] = 0.f; lp1[lane] = 0.f; }
    __syncthreads();

    float run[16];
    #pragma unroll
    for (int i = 0; i < 16; ++i) run[i] = 0.f;

    for (int r = 0; r < SEG; r += 2) {
        const int y0 = yseg * SEG + r;
        float a0[16], a1[16];
        #pragma unroll
        for (int k = 0; k < 4; ++k) {
            float4 v0 = *(const float4*)(carow + (size_t)y0 * WW + 4 * k);
            float4 v1 = *(const float4*)(carow + (size_t)(y0 + 1) * WW + 4 * k);
            a0[4*k+0] = v0.x + EPSV; a0[4*k+1] = v0.y + EPSV;
            a0[4*k+2] = v0.z + EPSV; a0[4*k+3] = v0.w + EPSV;
            a1[4*k+0] = v1.x + EPSV; a1[4*k+1] = v1.y + EPSV;
            a1[4*k+2] = v1.z + EPSV; a1[4*k+3] = v1.w + EPSV;
        }
        if (p < 8) {
            #pragma unroll
            for (int k = 0; k < 4; ++k) {
                float4 v0 = *(const float4*)(nnrow + (size_t)y0 * WW + 4 * k);
                float4 v1 = *(const float4*)(nnrow + (size_t)(y0 + 1) * WW + 4 * k);
                a0[4*k+0] *= v0.x; a0[4*k+1] *= v0.y;
                a0[4*k+2] *= v0.z; a0[4*k+3] *= v0.w;
                a1[4*k+0] *= v1.x; a1[4*k+1] *= v1.y;
                a1[4*k+2] *= v1.z; a1[4*k+3] *= v1.w;
            }
        }
        #pragma unroll
        for (int i = 1; i < 16; ++i) { a0[i] += a0[i-1]; a1[i] += a1[i-1]; }
        float tot0 = a0[15], tot1 = a1[15];
        float sc0 = tot0, sc1 = tot1;
        #pragma unroll
        for (int off = 1; off < 64; off <<= 1) {
            float v0 = __shfl_up(sc0, off);
            float v1 = __shfl_up(sc1, off);
            if (lane >= off) { sc0 += v0; sc1 += v1; }
        }
        float base0 = sc0 - tot0, base1 = sc1 - tot1;
        float total0 = __shfl(sc0, 63);
        float total1 = __shfl(sc1, 63);
        // ---- publish absolute prefixes: swizzled b128 writes ----
        #pragma unroll
        for (int k = 0; k < 4; ++k) {
            f32x4 v0, v1;
            v0.x = a0[4*k+0] + base0; v0.y = a0[4*k+1] + base0;
            v0.z = a0[4*k+2] + base0; v0.w = a0[4*k+3] + base0;
            v1.x = a1[4*k+0] + base1; v1.y = a1[4*k+1] + base1;
            v1.z = a1[4*k+2] + base1; v1.w = a1[4*k+3] + base1;
            *(f32x4*)&lp0[wg[k]] = v0;
            *(f32x4*)&lp1[wg[k]] = v1;
        }
        // tail (granules 264..271, all = total; value same under swizzle)
        if (lane < 32) {
            int tg = 4 * swz(264 + (lane >> 2)) + (lane & 3);
            lp0[tg] = total0; lp1[tg] = total1;
        }
        __syncthreads();

        // ---- row 0 ----
        u32 pk[8];
        {
            f32x4 Hr[5], Lr[5];
            #pragma unroll
            for (int k = 0; k < 5; ++k) {
                Hr[k] = *(const f32x4*)&lp0[hg[k]];
                Lr[k] = *(const f32x4*)&lp0[lg[k]];
            }
            #pragma unroll
            for (int i = 0; i < 16; ++i) {
                float hi = Hr[(i+1) >> 2][(i+1) & 3];
                float lo = Lr[(i+2) >> 2][(i+2) & 3];
                run[i] += hi - lo;
            }
            #pragma unroll
            for (int j = 0; j < 8; ++j)
                pk[j] = (u32)bf16r(run[2*j]) | ((u32)bf16r(run[2*j+1]) << 16);
            u16* dst0 = PH + ((size_t)pl * HH + y0) * WW + x0;
            u32x4 q0; q0.x = pk[0]; q0.y = pk[1]; q0.z = pk[2]; q0.w = pk[3];
            u32x4 q1; q1.x = pk[4]; q1.y = pk[5]; q1.z = pk[6]; q1.w = pk[7];
            *(u32x4*)dst0       = q0;
            *(u32x4*)(dst0 + 8) = q1;
        }
        // ---- row 1 ----
        {
            f32x4 Hr[5], Lr[5];
            #pragma unroll
            for (int k = 0; k < 5; ++k) {
                Hr[k] = *(const f32x4*)&lp1[hg[k]];
                Lr[k] = *(const f32x4*)&lp1[lg[k]];
            }
            #pragma unroll
            for (int i = 0; i < 16; ++i) {
                float hi = Hr[(i+1) >> 2][(i+1) & 3];
                float lo = Lr[(i+2) >> 2][(i+2) & 3];
                run[i] += hi - lo;
            }
            #pragma unroll
            for (int j = 0; j < 8; ++j)
                pk[j] = (u32)bf16r(run[2*j]) | ((u32)bf16r(run[2*j+1]) << 16);
            u16* dst1 = PH + ((size_t)pl * HH + y0 + 1) * WW + x0;
            u32x4 q0; q0.x = pk[0]; q0.y = pk[1]; q0.z = pk[2]; q0.w = pk[3];
            u32x4 q1; q1.x = pk[4]; q1.y = pk[5]; q1.z = pk[6]; q1.w = pk[7];
            *(u32x4*)dst1       = q0;
            *(u32x4*)(dst1 + 8) = q1;
        }
        __syncthreads();
    }
    // segment totals (f32, exact)
    float* st = SegT + ((size_t)pl * NSEG + yseg) * WW + x0;
    #pragma unroll
    for (int k = 0; k < 4; ++k) {
        f32x4 v; v.x = run[4*k+0]; v.y = run[4*k+1];
        v.z = run[4*k+2]; v.w = run[4*k+3];
        *(f32x4*)(st + 4 * k) = v;
    }
}

// =====================================================================
// K1b: exclusive scan of segment totals over the 64 segments.
// =====================================================================
__global__ __launch_bounds__(256) void segscan(const float* __restrict__ SegT,
                                               float* __restrict__ Off) {
    int p = blockIdx.x;
    int x = blockIdx.y * 256 + threadIdx.x;
    const float* s = SegT + (size_t)p * NSEG * WW + x;
    float*       o = Off  + (size_t)p * NSEG * WW + x;
    float acc = 0.f;
    for (int sg = 0; sg < NSEG; ++sg) {
        float v = s[(size_t)sg * WW];
        o[(size_t)sg * WW] = acc;
        acc += v;
    }
}

// =====================================================================
// windowV: vertical 51-window of a plane via prefix difference.
// =====================================================================
struct F4 { float v0, v1, v2, v3; };

__device__ __forceinline__ F4 windowV(const u16* __restrict__ PH,
                                      const float* __restrict__ Off,
                                      int pl, int yhi, int shi, int haslo,
                                      int ylo, int slo, int x0) {
    ushort4 uh = *(const ushort4*)(PH + ((size_t)pl * HH + yhi) * WW + x0);
    float4  oh = *(const float4*)(Off + ((size_t)pl * NSEG + shi) * WW + x0);
    F4 r;
    r.v0 = __uint_as_float((u32)uh.x << 16) + oh.x;
    r.v1 = __uint_as_float((u32)uh.y << 16) + oh.y;
    r.v2 = __uint_as_float((u32)uh.z << 16) + oh.z;
    r.v3 = __uint_as_float((u32)uh.w << 16) + oh.w;
    if (haslo) {
        ushort4 ul = *(const ushort4*)(PH + ((size_t)pl * HH + ylo) * WW + x0);
        float4  ol = *(const float4*)(Off + ((size_t)pl * NSEG + slo) * WW + x0);
        r.v0 -= __uint_as_float((u32)ul.x << 16) + ol.x;
        r.v1 -= __uint_as_float((u32)ul.y << 16) + ol.y;
        r.v2 -= __uint_as_float((u32)ul.z << 16) + ol.z;
        r.v3 -= __uint_as_float((u32)ul.w << 16) + ol.w;
    }
    return r;
}

// =====================================================================
// K2 (fused): out[l,y,x] = sum_c (ca+EPS)/V(norm) * V(joint).
// wgtk folded in: the norm windows + divide are recomputed per l-pair
// block (norm PH set = 17 MB, L2/L3-hot; divide cheap at this
// occupancy) instead of materializing 33 MB Wgt + 133 MB re-reads.
// grid 4096 blocks, XCD-swizzled as before.
// =====================================================================
__global__ __launch_bounds__(256) void vcombine6(const float* __restrict__ ca,
                                                 const u16* __restrict__ PH,
                                                 const float* __restrict__ Off,
                                                 float* __restrict__ out) {
    const int b    = blockIdx.x;           // 0..4095
    const int work = (b & 7) * 512 + (b >> 3);  // bijective XCD swizzle
    const int y    = work >> 2;
    const int l0   = (work & 3) << 1;
    const int t  = threadIdx.x;
    const int x0 = 4 * t;
    const int yhi   = (y + RAD > HH - 1) ? HH - 1 : y + RAD;
    const int shi   = yhi / SEG;
    const int haslo = (y - RAD - 1 >= 0) ? 1 : 0;
    const int ylo   = haslo ? y - RAD - 1 : 0;
    const int slo   = ylo / SEG;

    float a00 = 0.f, a01 = 0.f, a02 = 0.f, a03 = 0.f;
    float a10 = 0.f, a11 = 0.f, a12 = 0.f, a13 = 0.f;

    #pragma unroll
    for (int c = 0; c < CC; ++c) {
        F4 Vn = windowV(PH, Off, 64 + c, yhi, shi, haslo, ylo, slo, x0);
        float4 oc4 = *(const float4*)(ca + ((size_t)c * HH + y) * WW + x0);
        float w0 = (oc4.x + EPSV) / Vn.v0;
        float w1 = (oc4.y + EPSV) / Vn.v1;
        float w2 = (oc4.z + EPSV) / Vn.v2;
        float w3 = (oc4.w + EPSV) / Vn.v3;
        F4 Vj0 = windowV(PH, Off, c * LL + l0,     yhi, shi, haslo, ylo, slo, x0);
        F4 Vj1 = windowV(PH, Off, c * LL + l0 + 1, yhi, shi, haslo, ylo, slo, x0);
        a00 += w0 * Vj0.v0; a01 += w1 * Vj0.v1;
        a02 += w2 * Vj0.v2; a03 += w3 * Vj0.v3;
        a10 += w0 * Vj1.v0; a11 += w1 * Vj1.v1;
        a12 += w2 * Vj1.v2; a13 += w3 * Vj1.v3;
    }
    float4 o0; o0.x = a00; o0.y = a01; o0.z = a02; o0.w = a03;
    float4 o1; o1.x = a10; o1.y = a11; o1.z = a12; o1.w = a13;
    *(float4*)(out + ((size_t)(l0 + 0) * HH + y) * WW + x0) = o0;
    *(float4*)(out + ((size_t)(l0 + 1) * HH + y) * WW + x0) = o1;
}

// =====================================================================

extern "C" void kernel_launch(void* const* d_in, const int* in_sizes, int n_in,
                              void* d_out, int out_size, void* d_ws, size_t ws_size,
                              hipStream_t stream) {
    const float* ca = (const float*)d_in[0];   // (8,1024,1024)
    const float* nn = (const float*)d_in[1];   // (1,8,1024,1024)
    float* out = (float*)d_out;                // (8,1024,1024)

    // workspace: PH bf16 [72][H][W] (151 MB) | SegT f32 (19 MB)
    //            | Off f32 (19 MB)  => 189 MB
    u16*   PH   = (u16*)d_ws;
    float* SegT = (float*)((char*)d_ws + (size_t)NPL * HH * WW * sizeof(u16));
    float* Off  = SegT + (size_t)NPL * NSEG * WW;

    hprefix8<<<dim3(NBLK), 128, 0, stream>>>(ca, nn, PH, SegT);
    segscan<<<dim3(NPL, 4), 256, 0, stream>>>(SegT, Off);
    vcombine6<<<dim3(HH * 4), 256, 0, stream>>>(ca, PH, Off, out);
}

// Round 21
// 183.690 us; speedup vs baseline: 1.1309x; 1.1309x over previous
//
#include <hip/hip_runtime.h>
#include <hip/hip_bf16.h>

#define HH 1024
#define WW 1024
#define CC 8
#define LL 8
#define RAD 25
#define EPSV 1e-6f
#define SEG 16              // rows per vertical prefix segment
#define NSEG (HH / SEG)     // 64
#define NPL 72              // 64 joint planes + 8 oc planes
#define NTASK (NSEG * CC * 9)   // 4608 wave-tasks
#define NBLK  (NTASK / 2)       // 2304 blocks (2 waves each)
#define BPX   (NBLK / 8)        // 288 blocks per XCD chunk

typedef unsigned short u16;
typedef unsigned int   u32;
typedef u32   u32x4 __attribute__((ext_vector_type(4)));
typedef float f32x4 __attribute__((ext_vector_type(4)));

__device__ __forceinline__ u16 bf16r(float x) {
    u32 b = __float_as_uint(x);
    b += 0x7FFFu + ((b >> 16) & 1u);     // round-to-nearest-even
    return (u16)(b >> 16);
}

// 16B-granule XOR swizzle (R18: conflicts 18.4M -> 3.4M).
__device__ __forceinline__ int swz(int g) { return g ^ ((g >> 3) & 7); }

// Wave-local LDS fence: Pbuf[w] is private to this wave, so instead of
// __syncthreads (which lockstep-couples the block's two INDEPENDENT
// wave-tasks), drain our own ds ops and pin the scheduler. "memory"
// clobber orders the surrounding ds_read/ds_write (both are memory ops);
// sched_barrier(0) blocks post-RA hoisting (guide rule #18).
__device__ __forceinline__ void wave_lds_fence() {
    asm volatile("s_waitcnt lgkmcnt(0)" ::: "memory");
    __builtin_amdgcn_sched_barrier(0);
}

// =====================================================================
// K1: per-row horizontal 51-window sums, one WAVE per (segment, c, plane)
// task; rows in PAIRS. LDS float layout: [32 zeros][1024 prefix][32 total]
// stored as XOR-swizzled 16B granules. Wave-local fences (not barriers)
// at the write->read boundaries: the two waves run decoupled.
// =====================================================================
__global__ __launch_bounds__(128) void hprefix9(const float* __restrict__ ca,
                                                const float* __restrict__ nn,
                                                u16* __restrict__ PH,
                                                float* __restrict__ SegT) {
    const int t    = threadIdx.x;
    const int lane = t & 63;
    const int w    = t >> 6;               // wave in block 0..1
    const int blk  = blockIdx.x;           // 0..2303
    const int task = ((blk & 7) * BPX + (blk >> 3)) * 2 + w;   // 0..4607
    const int yseg = task / (CC * 9);
    const int rem  = task - yseg * (CC * 9);
    const int c    = rem / 9;
    const int p    = rem - c * 9;          // 0..7 joint, 8 = oc plane

    __shared__ __align__(16) float Pbuf[2][2][1088];
    float* __restrict__ lp0 = Pbuf[w][0];
    float* __restrict__ lp1 = Pbuf[w][1];

    const int pl = (p < 8) ? (c * 8 + p) : (64 + c);
    const float* carow = ca + (size_t)c * HH * WW + 16 * lane;
    const float* nnrow = nn + (size_t)(p < 8 ? p : 0) * HH * WW + 16 * lane;
    const int x0 = 16 * lane;

    // precomputed swizzled float offsets (loop-invariant)
    int wg[4], hg[5], lg[5];
    #pragma unroll
    for (int k = 0; k < 4; ++k) wg[k] = 4 * swz(8 + 4 * lane + k);
    #pragma unroll
    for (int k = 0; k < 5; ++k) {
        hg[k] = 4 * swz(14 + 4 * lane + k);
        lg[k] = 4 * swz(1 + 4 * lane + k);
    }

    // zero head (granules 0..7 are identity under swz)
    if (lane < 32) { lp0[lane] = 0.f; lp1[lane] = 0.f; }
    wave_lds_fence();

    float run[16];
    #pragma unroll
    for (int i = 0; i < 16; ++i) run[i] = 0.f;

    for (int r = 0; r < SEG; r += 2) {
        const int y0 = yseg * SEG + r;
        float a0[16], a1[16];
        #pragma unroll
        for (int k = 0; k < 4; ++k) {
            float4 v0 = *(const float4*)(carow + (size_t)y0 * WW + 4 * k);
            float4 v1 = *(const float4*)(carow + (size_t)(y0 + 1) * WW + 4 * k);
            a0[4*k+0] = v0.x + EPSV; a0[4*k+1] = v0.y + EPSV;
            a0[4*k+2] = v0.z + EPSV; a0[4*k+3] = v0.w + EPSV;
            a1[4*k+0] = v1.x + EPSV; a1[4*k+1] = v1.y + EPSV;
            a1[4*k+2] = v1.z + EPSV; a1[4*k+3] = v1.w + EPSV;
        }
        if (p < 8) {
            #pragma unroll
            for (int k = 0; k < 4; ++k) {
                float4 v0 = *(const float4*)(nnrow + (size_t)y0 * WW + 4 * k);
                float4 v1 = *(const float4*)(nnrow + (size_t)(y0 + 1) * WW + 4 * k);
                a0[4*k+0] *= v0.x; a0[4*k+1] *= v0.y;
                a0[4*k+2] *= v0.z; a0[4*k+3] *= v0.w;
                a1[4*k+0] *= v1.x; a1[4*k+1] *= v1.y;
                a1[4*k+2] *= v1.z; a1[4*k+3] *= v1.w;
            }
        }
        #pragma unroll
        for (int i = 1; i < 16; ++i) { a0[i] += a0[i-1]; a1[i] += a1[i-1]; }
        float tot0 = a0[15], tot1 = a1[15];
        float sc0 = tot0, sc1 = tot1;
        #pragma unroll
        for (int off = 1; off < 64; off <<= 1) {
            float v0 = __shfl_up(sc0, off);
            float v1 = __shfl_up(sc1, off);
            if (lane >= off) { sc0 += v0; sc1 += v1; }
        }
        float base0 = sc0 - tot0, base1 = sc1 - tot1;
        float total0 = __shfl(sc0, 63);
        float total1 = __shfl(sc1, 63);
        // ---- publish absolute prefixes: swizzled b128 writes ----
        #pragma unroll
        for (int k = 0; k < 4; ++k) {
            f32x4 v0, v1;
            v0.x = a0[4*k+0] + base0; v0.y = a0[4*k+1] + base0;
            v0.z = a0[4*k+2] + base0; v0.w = a0[4*k+3] + base0;
            v1.x = a1[4*k+0] + base1; v1.y = a1[4*k+1] + base1;
            v1.z = a1[4*k+2] + base1; v1.w = a1[4*k+3] + base1;
            *(f32x4*)&lp0[wg[k]] = v0;
            *(f32x4*)&lp1[wg[k]] = v1;
        }
        // tail (granules 264..271, all = total; value same under swizzle)
        if (lane < 32) {
            int tg = 4 * swz(264 + (lane >> 2)) + (lane & 3);
            lp0[tg] = total0; lp1[tg] = total1;
        }
        wave_lds_fence();                  // our writes drained, no hoisting

        // ---- row 0 ----
        u32 pk[8];
        {
            f32x4 Hr[5], Lr[5];
            #pragma unroll
            for (int k = 0; k < 5; ++k) {
                Hr[k] = *(const f32x4*)&lp0[hg[k]];
                Lr[k] = *(const f32x4*)&lp0[lg[k]];
            }
            #pragma unroll
            for (int i = 0; i < 16; ++i) {
                float hi = Hr[(i+1) >> 2][(i+1) & 3];
                float lo = Lr[(i+2) >> 2][(i+2) & 3];
                run[i] += hi - lo;
            }
            #pragma unroll
            for (int j = 0; j < 8; ++j)
                pk[j] = (u32)bf16r(run[2*j]) | ((u32)bf16r(run[2*j+1]) << 16);
            u16* dst0 = PH + ((size_t)pl * HH + y0) * WW + x0;
            u32x4 q0; q0.x = pk[0]; q0.y = pk[1]; q0.z = pk[2]; q0.w = pk[3];
            u32x4 q1; q1.x = pk[4]; q1.y = pk[5]; q1.z = pk[6]; q1.w = pk[7];
            *(u32x4*)dst0       = q0;
            *(u32x4*)(dst0 + 8) = q1;
        }
        // ---- row 1 ----
        {
            f32x4 Hr[5], Lr[5];
            #pragma unroll
            for (int k = 0; k < 5; ++k) {
                Hr[k] = *(const f32x4*)&lp1[hg[k]];
                Lr[k] = *(const f32x4*)&lp1[lg[k]];
            }
            #pragma unroll
            for (int i = 0; i < 16; ++i) {
                float hi = Hr[(i+1) >> 2][(i+1) & 3];
                float lo = Lr[(i+2) >> 2][(i+2) & 3];
                run[i] += hi - lo;
            }
            #pragma unroll
            for (int j = 0; j < 8; ++j)
                pk[j] = (u32)bf16r(run[2*j]) | ((u32)bf16r(run[2*j+1]) << 16);
            u16* dst1 = PH + ((size_t)pl * HH + y0 + 1) * WW + x0;
            u32x4 q0; q0.x = pk[0]; q0.y = pk[1]; q0.z = pk[2]; q0.w = pk[3];
            u32x4 q1; q1.x = pk[4]; q1.y = pk[5]; q1.z = pk[6]; q1.w = pk[7];
            *(u32x4*)dst1       = q0;
            *(u32x4*)(dst1 + 8) = q1;
        }
        wave_lds_fence();                  // reads done before next-iter writes
    }
    // segment totals (f32, exact)
    float* st = SegT + ((size_t)pl * NSEG + yseg) * WW + x0;
    #pragma unroll
    for (int k = 0; k < 4; ++k) {
        f32x4 v; v.x = run[4*k+0]; v.y = run[4*k+1];
        v.z = run[4*k+2]; v.w = run[4*k+3];
        *(f32x4*)(st + 4 * k) = v;
    }
}

// =====================================================================
// K1b: exclusive scan of segment totals over the 64 segments.
// =====================================================================
__global__ __launch_bounds__(256) void segscan(const float* __restrict__ SegT,
                                               float* __restrict__ Off) {
    int p = blockIdx.x;
    int x = blockIdx.y * 256 + threadIdx.x;
    const float* s = SegT + (size_t)p * NSEG * WW + x;
    float*       o = Off  + (size_t)p * NSEG * WW + x;
    float acc = 0.f;
    for (int sg = 0; sg < NSEG; ++sg) {
        float v = s[(size_t)sg * WW];
        o[(size_t)sg * WW] = acc;
        acc += v;
    }
}

// =====================================================================
// windowV: vertical 51-window of a plane via prefix difference.
// =====================================================================
struct F4 { float v0, v1, v2, v3; };

__device__ __forceinline__ F4 windowV(const u16* __restrict__ PH,
                                      const float* __restrict__ Off,
                                      int pl, int yhi, int shi, int haslo,
                                      int ylo, int slo, int x0) {
    ushort4 uh = *(const ushort4*)(PH + ((size_t)pl * HH + yhi) * WW + x0);
    float4  oh = *(const float4*)(Off + ((size_t)pl * NSEG + shi) * WW + x0);
    F4 r;
    r.v0 = __uint_as_float((u32)uh.x << 16) + oh.x;
    r.v1 = __uint_as_float((u32)uh.y << 16) + oh.y;
    r.v2 = __uint_as_float((u32)uh.z << 16) + oh.z;
    r.v3 = __uint_as_float((u32)uh.w << 16) + oh.w;
    if (haslo) {
        ushort4 ul = *(const ushort4*)(PH + ((size_t)pl * HH + ylo) * WW + x0);
        float4  ol = *(const float4*)(Off + ((size_t)pl * NSEG + slo) * WW + x0);
        r.v0 -= __uint_as_float((u32)ul.x << 16) + ol.x;
        r.v1 -= __uint_as_float((u32)ul.y << 16) + ol.y;
        r.v2 -= __uint_as_float((u32)ul.z << 16) + ol.z;
        r.v3 -= __uint_as_float((u32)ul.w << 16) + ol.w;
    }
    return r;
}

// =====================================================================
// K1c: weights Wgt[c][y][x] = (ca+EPS) / Vn.
// =====================================================================
__global__ __launch_bounds__(256) void wgtk(const float* __restrict__ ca,
                                            const u16* __restrict__ PH,
                                            const float* __restrict__ Off,
                                            float* __restrict__ Wgt) {
    const int b   = blockIdx.x;            // 0..1023
    const int y   = (b & 7) * 128 + (b >> 3);   // bijective XCD swizzle
    const int t   = threadIdx.x;
    const int x0  = 4 * t;
    const int yhi   = (y + RAD > HH - 1) ? HH - 1 : y + RAD;
    const int shi   = yhi / SEG;
    const int haslo = (y - RAD - 1 >= 0) ? 1 : 0;
    const int ylo   = haslo ? y - RAD - 1 : 0;
    const int slo   = ylo / SEG;

    #pragma unroll
    for (int c = 0; c < CC; ++c) {
        F4 Vn = windowV(PH, Off, 64 + c, yhi, shi, haslo, ylo, slo, x0);
        float4 oc4 = *(const float4*)(ca + ((size_t)c * HH + y) * WW + x0);
        float4 w;
        w.x = (oc4.x + EPSV) / Vn.v0;
        w.y = (oc4.y + EPSV) / Vn.v1;
        w.z = (oc4.z + EPSV) / Vn.v2;
        w.w = (oc4.w + EPSV) / Vn.v3;
        *(float4*)(Wgt + ((size_t)c * HH + y) * WW + x0) = w;
    }
}

// =====================================================================
// K2: out[l,y,x] = sum_c Wgt * V(joint). grid 4096 blocks, XCD-swizzled.
// =====================================================================
__global__ __launch_bounds__(256) void vcombine3(const float* __restrict__ Wgt,
                                                 const u16* __restrict__ PH,
                                                 const float* __restrict__ Off,
                                                 float* __restrict__ out) {
    const int b    = blockIdx.x;           // 0..4095
    const int work = (b & 7) * 512 + (b >> 3);  // bijective XCD swizzle
    const int y    = work >> 2;
    const int l0   = (work & 3) << 1;
    const int t  = threadIdx.x;
    const int x0 = 4 * t;
    const int yhi   = (y + RAD > HH - 1) ? HH - 1 : y + RAD;
    const int shi   = yhi / SEG;
    const int haslo = (y - RAD - 1 >= 0) ? 1 : 0;
    const int ylo   = haslo ? y - RAD - 1 : 0;
    const int slo   = ylo / SEG;

    float a00 = 0.f, a01 = 0.f, a02 = 0.f, a03 = 0.f;
    float a10 = 0.f, a11 = 0.f, a12 = 0.f, a13 = 0.f;

    #pragma unroll
    for (int c = 0; c < CC; ++c) {
        float4 w4 = *(const float4*)(Wgt + ((size_t)c * HH + y) * WW + x0);
        F4 Vj0 = windowV(PH, Off, c * LL + l0,     yhi, shi, haslo, ylo, slo, x0);
        F4 Vj1 = windowV(PH, Off, c * LL + l0 + 1, yhi, shi, haslo, ylo, slo, x0);
        a00 += w4.x * Vj0.v0; a01 += w4.y * Vj0.v1;
        a02 += w4.z * Vj0.v2; a03 += w4.w * Vj0.v3;
        a10 += w4.x * Vj1.v0; a11 += w4.y * Vj1.v1;
        a12 += w4.z * Vj1.v2; a13 += w4.w * Vj1.v3;
    }
    float4 o0; o0.x = a00; o0.y = a01; o0.z = a02; o0.w = a03;
    float4 o1; o1.x = a10; o1.y = a11; o1.z = a12; o1.w = a13;
    *(float4*)(out + ((size_t)(l0 + 0) * HH + y) * WW + x0) = o0;
    *(float4*)(out + ((size_t)(l0 + 1) * HH + y) * WW + x0) = o1;
}

// =====================================================================

extern "C" void kernel_launch(void* const* d_in, const int* in_sizes, int n_in,
                              void* d_out, int out_size, void* d_ws, size_t ws_size,
                              hipStream_t stream) {
    const float* ca = (const float*)d_in[0];   // (8,1024,1024)
    const float* nn = (const float*)d_in[1];   // (1,8,1024,1024)
    float* out = (float*)d_out;                // (8,1024,1024)

    // workspace: PH bf16 [72][H][W] (151 MB) | SegT f32 (19 MB)
    //            | Off f32 (19 MB) | Wgt f32 [8][H][W] (33.5 MB) => 222 MB
    u16*   PH   = (u16*)d_ws;
    float* SegT = (float*)((char*)d_ws + (size_t)NPL * HH * WW * sizeof(u16));
    float* Off  = SegT + (size_t)NPL * NSEG * WW;
    float* Wgt  = Off  + (size_t)NPL * NSEG * WW;

    hprefix9<<<dim3(NBLK), 128, 0, stream>>>(ca, nn, PH, SegT);
    segscan<<<dim3(NPL, 4), 256, 0, stream>>>(SegT, Off);
    wgtk<<<dim3(HH), 256, 0, stream>>>(ca, PH, Off, Wgt);
    vcombine3<<<dim3(HH * 4), 256, 0, stream>>>(Wgt, PH, Off, out);
}

// Round 22
// 175.616 us; speedup vs baseline: 1.1829x; 1.0460x over previous
//
#include <hip/hip_runtime.h>
#include <hip/hip_bf16.h>

#define HH 1024
#define WW 1024
#define CC 8
#define LL 8
#define RAD 25
#define EPSV 1e-6f
#define SEG 16              // rows per vertical prefix segment
#define NSEG (HH / SEG)     // 64
#define NPL 72              // 64 joint planes + 8 oc planes
#define NTASK (NSEG * CC * 9)   // 4608 wave-tasks
#define NBLK  (NTASK / 2)       // 2304 blocks (2 waves each)
#define BPX   (NBLK / 8)        // 288 blocks per XCD chunk

typedef unsigned short u16;
typedef unsigned int   u32;
typedef u32   u32x4 __attribute__((ext_vector_type(4)));
typedef float f32x4 __attribute__((ext_vector_type(4)));

__device__ __forceinline__ u16 bf16r(float x) {
    u32 b = __float_as_uint(x);
    b += 0x7FFFu + ((b >> 16) & 1u);     // round-to-nearest-even
    return (u16)(b >> 16);
}

// 16B-granule XOR swizzle (R18: conflicts 18.4M -> 3.4M).
__device__ __forceinline__ int swz(int g) { return g ^ ((g >> 3) & 7); }

// Wave-local LDS fence: drains this wave's ds ops; the "memory" clobber
// is a compiler memory barrier so ds_read/ds_write can't cross (they are
// memory ops, unlike R15's register-only case). No sched_barrier: global
// prefetch loads placed ABOVE it in source stay above it, and nothing
// else needs pinning.
__device__ __forceinline__ void wave_lds_fence() {
    asm volatile("s_waitcnt lgkmcnt(0)" ::: "memory");
}

// =====================================================================
// K1: per-row horizontal 51-window sums, one WAVE per (segment, c, plane)
// task; rows in PAIRS with DEPTH-1 SOFTWARE PREFETCH: pair q+1's global
// loads are issued before pair q's scan/LDS work, so each wave always
// has 8 loads in flight covering ~an iteration of latency. Two named
// register sets (A/B), parity-unrolled (no runtime indexing -> no
// scratch). LDS: [32 zeros][1024 prefix][32 total], XOR-swizzled 16B
// granules, b128 traffic.
// =====================================================================
__global__ __launch_bounds__(128) void hprefix10(const float* __restrict__ ca,
                                                 const float* __restrict__ nn,
                                                 u16* __restrict__ PH,
                                                 float* __restrict__ SegT) {
    const int t    = threadIdx.x;
    const int lane = t & 63;
    const int w    = t >> 6;               // wave in block 0..1
    const int blk  = blockIdx.x;           // 0..2303
    const int task = ((blk & 7) * BPX + (blk >> 3)) * 2 + w;   // 0..4607
    const int yseg = task / (CC * 9);
    const int rem  = task - yseg * (CC * 9);
    const int c    = rem / 9;
    const int p    = rem - c * 9;          // 0..7 joint, 8 = oc plane

    __shared__ __align__(16) float Pbuf[2][2][1088];
    float* __restrict__ lp0 = Pbuf[w][0];
    float* __restrict__ lp1 = Pbuf[w][1];

    const int pl = (p < 8) ? (c * 8 + p) : (64 + c);
    const float* carow = ca + (size_t)c * HH * WW + 16 * lane;
    const float* nnrow = nn + (size_t)(p < 8 ? p : 0) * HH * WW + 16 * lane;
    const int x0 = 16 * lane;

    // precomputed swizzled float offsets (loop-invariant)
    int wg[4], hg[5], lg[5];
    #pragma unroll
    for (int k = 0; k < 4; ++k) wg[k] = 4 * swz(8 + 4 * lane + k);
    #pragma unroll
    for (int k = 0; k < 5; ++k) {
        hg[k] = 4 * swz(14 + 4 * lane + k);
        lg[k] = 4 * swz(1 + 4 * lane + k);
    }

    // zero head (granules 0..7 are identity under swz)
    if (lane < 32) { lp0[lane] = 0.f; lp1[lane] = 0.f; }
    wave_lds_fence();

    float run[16];
    #pragma unroll
    for (int i = 0; i < 16; ++i) run[i] = 0.f;

    float4 cA[2][4], nA[2][4], cB[2][4], nB[2][4];

    auto loadpair = [&](float4 (&CA)[2][4], float4 (&NA)[2][4], int yy) {
        #pragma unroll
        for (int k = 0; k < 4; ++k) {
            CA[0][k] = *(const float4*)(carow + (size_t)yy * WW + 4 * k);
            CA[1][k] = *(const float4*)(carow + (size_t)(yy + 1) * WW + 4 * k);
        }
        if (p < 8) {
            #pragma unroll
            for (int k = 0; k < 4; ++k) {
                NA[0][k] = *(const float4*)(nnrow + (size_t)yy * WW + 4 * k);
                NA[1][k] = *(const float4*)(nnrow + (size_t)(yy + 1) * WW + 4 * k);
            }
        }
    };

    auto process = [&](const float4 (&CA)[2][4], const float4 (&NA)[2][4],
                       int y0) {
        float a0[16], a1[16];
        #pragma unroll
        for (int k = 0; k < 4; ++k) {
            a0[4*k+0] = CA[0][k].x + EPSV; a0[4*k+1] = CA[0][k].y + EPSV;
            a0[4*k+2] = CA[0][k].z + EPSV; a0[4*k+3] = CA[0][k].w + EPSV;
            a1[4*k+0] = CA[1][k].x + EPSV; a1[4*k+1] = CA[1][k].y + EPSV;
            a1[4*k+2] = CA[1][k].z + EPSV; a1[4*k+3] = CA[1][k].w + EPSV;
        }
        if (p < 8) {
            #pragma unroll
            for (int k = 0; k < 4; ++k) {
                a0[4*k+0] *= NA[0][k].x; a0[4*k+1] *= NA[0][k].y;
                a0[4*k+2] *= NA[0][k].z; a0[4*k+3] *= NA[0][k].w;
                a1[4*k+0] *= NA[1][k].x; a1[4*k+1] *= NA[1][k].y;
                a1[4*k+2] *= NA[1][k].z; a1[4*k+3] *= NA[1][k].w;
            }
        }
        #pragma unroll
        for (int i = 1; i < 16; ++i) { a0[i] += a0[i-1]; a1[i] += a1[i-1]; }
        float tot0 = a0[15], tot1 = a1[15];
        float sc0 = tot0, sc1 = tot1;
        #pragma unroll
        for (int off = 1; off < 64; off <<= 1) {
            float v0 = __shfl_up(sc0, off);
            float v1 = __shfl_up(sc1, off);
            if (lane >= off) { sc0 += v0; sc1 += v1; }
        }
        float base0 = sc0 - tot0, base1 = sc1 - tot1;
        float total0 = __shfl(sc0, 63);
        float total1 = __shfl(sc1, 63);
        // publish absolute prefixes: swizzled b128 writes
        #pragma unroll
        for (int k = 0; k < 4; ++k) {
            f32x4 v0, v1;
            v0.x = a0[4*k+0] + base0; v0.y = a0[4*k+1] + base0;
            v0.z = a0[4*k+2] + base0; v0.w = a0[4*k+3] + base0;
            v1.x = a1[4*k+0] + base1; v1.y = a1[4*k+1] + base1;
            v1.z = a1[4*k+2] + base1; v1.w = a1[4*k+3] + base1;
            *(f32x4*)&lp0[wg[k]] = v0;
            *(f32x4*)&lp1[wg[k]] = v1;
        }
        // tail (granules 264..271, all = total)
        if (lane < 32) {
            int tg = 4 * swz(264 + (lane >> 2)) + (lane & 3);
            lp0[tg] = total0; lp1[tg] = total1;
        }
        wave_lds_fence();                  // writes drained before reads

        u32 pk[8];
        {   // row 0
            f32x4 Hr[5], Lr[5];
            #pragma unroll
            for (int k = 0; k < 5; ++k) {
                Hr[k] = *(const f32x4*)&lp0[hg[k]];
                Lr[k] = *(const f32x4*)&lp0[lg[k]];
            }
            #pragma unroll
            for (int i = 0; i < 16; ++i) {
                float hi = Hr[(i+1) >> 2][(i+1) & 3];
                float lo = Lr[(i+2) >> 2][(i+2) & 3];
                run[i] += hi - lo;
            }
            #pragma unroll
            for (int j = 0; j < 8; ++j)
                pk[j] = (u32)bf16r(run[2*j]) | ((u32)bf16r(run[2*j+1]) << 16);
            u16* dst0 = PH + ((size_t)pl * HH + y0) * WW + x0;
            u32x4 q0; q0.x = pk[0]; q0.y = pk[1]; q0.z = pk[2]; q0.w = pk[3];
            u32x4 q1; q1.x = pk[4]; q1.y = pk[5]; q1.z = pk[6]; q1.w = pk[7];
            *(u32x4*)dst0       = q0;
            *(u32x4*)(dst0 + 8) = q1;
        }
        {   // row 1
            f32x4 Hr[5], Lr[5];
            #pragma unroll
            for (int k = 0; k < 5; ++k) {
                Hr[k] = *(const f32x4*)&lp1[hg[k]];
                Lr[k] = *(const f32x4*)&lp1[lg[k]];
            }
            #pragma unroll
            for (int i = 0; i < 16; ++i) {
                float hi = Hr[(i+1) >> 2][(i+1) & 3];
                float lo = Lr[(i+2) >> 2][(i+2) & 3];
                run[i] += hi - lo;
            }
            #pragma unroll
            for (int j = 0; j < 8; ++j)
                pk[j] = (u32)bf16r(run[2*j]) | ((u32)bf16r(run[2*j+1]) << 16);
            u16* dst1 = PH + ((size_t)pl * HH + y0 + 1) * WW + x0;
            u32x4 q0; q0.x = pk[0]; q0.y = pk[1]; q0.z = pk[2]; q0.w = pk[3];
            u32x4 q1; q1.x = pk[4]; q1.y = pk[5]; q1.z = pk[6]; q1.w = pk[7];
            *(u32x4*)dst1       = q0;
            *(u32x4*)(dst1 + 8) = q1;
        }
        wave_lds_fence();                  // reads done before next writes
    };

    const int ybase = yseg * SEG;
    loadpair(cA, nA, ybase);               // prologue: pair 0
    for (int q = 0; q < SEG / 2; q += 2) {
        const int y0 = ybase + 2 * q;
        // even pair: consume A, prefetch pair q+1 into B
        loadpair(cB, nB, y0 + 2);
        process(cA, nA, y0);
        // odd pair: consume B, prefetch pair q+2 into A (skip on last)
        if (q + 2 < SEG / 2) loadpair(cA, nA, y0 + 4);
        process(cB, nB, y0 + 2);
    }

    // segment totals (f32, exact)
    float* st = SegT + ((size_t)pl * NSEG + yseg) * WW + x0;
    #pragma unroll
    for (int k = 0; k < 4; ++k) {
        f32x4 v; v.x = run[4*k+0]; v.y = run[4*k+1];
        v.z = run[4*k+2]; v.w = run[4*k+3];
        *(f32x4*)(st + 4 * k) = v;
    }
}

// =====================================================================
// K1b: exclusive scan of segment totals over the 64 segments.
// =====================================================================
__global__ __launch_bounds__(256) void segscan(const float* __restrict__ SegT,
                                               float* __restrict__ Off) {
    int p = blockIdx.x;
    int x = blockIdx.y * 256 + threadIdx.x;
    const float* s = SegT + (size_t)p * NSEG * WW + x;
    float*       o = Off  + (size_t)p * NSEG * WW + x;
    float acc = 0.f;
    for (int sg = 0; sg < NSEG; ++sg) {
        float v = s[(size_t)sg * WW];
        o[(size_t)sg * WW] = acc;
        acc += v;
    }
}

// =====================================================================
// windowV: vertical 51-window of a plane via prefix difference.
// =====================================================================
struct F4 { float v0, v1, v2, v3; };

__device__ __forceinline__ F4 windowV(const u16* __restrict__ PH,
                                      const float* __restrict__ Off,
                                      int pl, int yhi, int shi, int haslo,
                                      int ylo, int slo, int x0) {
    ushort4 uh = *(const ushort4*)(PH + ((size_t)pl * HH + yhi) * WW + x0);
    float4  oh = *(const float4*)(Off + ((size_t)pl * NSEG + shi) * WW + x0);
    F4 r;
    r.v0 = __uint_as_float((u32)uh.x << 16) + oh.x;
    r.v1 = __uint_as_float((u32)uh.y << 16) + oh.y;
    r.v2 = __uint_as_float((u32)uh.z << 16) + oh.z;
    r.v3 = __uint_as_float((u32)uh.w << 16) + oh.w;
    if (haslo) {
        ushort4 ul = *(const ushort4*)(PH + ((size_t)pl * HH + ylo) * WW + x0);
        float4  ol = *(const float4*)(Off + ((size_t)pl * NSEG + slo) * WW + x0);
        r.v0 -= __uint_as_float((u32)ul.x << 16) + ol.x;
        r.v1 -= __uint_as_float((u32)ul.y << 16) + ol.y;
        r.v2 -= __uint_as_float((u32)ul.z << 16) + ol.z;
        r.v3 -= __uint_as_float((u32)ul.w << 16) + ol.w;
    }
    return r;
}

// =====================================================================
// K1c: weights Wgt[c][y][x] = (ca+EPS) / Vn.
// =====================================================================
__global__ __launch_bounds__(256) void wgtk(const float* __restrict__ ca,
                                            const u16* __restrict__ PH,
                                            const float* __restrict__ Off,
                                            float* __restrict__ Wgt) {
    const int b   = blockIdx.x;            // 0..1023
    const int y   = (b & 7) * 128 + (b >> 3);   // bijective XCD swizzle
    const int t   = threadIdx.x;
    const int x0  = 4 * t;
    const int yhi   = (y + RAD > HH - 1) ? HH - 1 : y + RAD;
    const int shi   = yhi / SEG;
    const int haslo = (y - RAD - 1 >= 0) ? 1 : 0;
    const int ylo   = haslo ? y - RAD - 1 : 0;
    const int slo   = ylo / SEG;

    #pragma unroll
    for (int c = 0; c < CC; ++c) {
        F4 Vn = windowV(PH, Off, 64 + c, yhi, shi, haslo, ylo, slo, x0);
        float4 oc4 = *(const float4*)(ca + ((size_t)c * HH + y) * WW + x0);
        float4 w;
        w.x = (oc4.x + EPSV) / Vn.v0;
        w.y = (oc4.y + EPSV) / Vn.v1;
        w.z = (oc4.z + EPSV) / Vn.v2;
        w.w = (oc4.w + EPSV) / Vn.v3;
        *(float4*)(Wgt + ((size_t)c * HH + y) * WW + x0) = w;
    }
}

// =====================================================================
// K2: out[l,y,x] = sum_c Wgt * V(joint). grid 4096 blocks, XCD-swizzled.
// =====================================================================
__global__ __launch_bounds__(256) void vcombine3(const float* __restrict__ Wgt,
                                                 const u16* __restrict__ PH,
                                                 const float* __restrict__ Off,
                                                 float* __restrict__ out) {
    const int b    = blockIdx.x;           // 0..4095
    const int work = (b & 7) * 512 + (b >> 3);  // bijective XCD swizzle
    const int y    = work >> 2;
    const int l0   = (work & 3) << 1;
    const int t  = threadIdx.x;
    const int x0 = 4 * t;
    const int yhi   = (y + RAD > HH - 1) ? HH - 1 : y + RAD;
    const int shi   = yhi / SEG;
    const int haslo = (y - RAD - 1 >= 0) ? 1 : 0;
    const int ylo   = haslo ? y - RAD - 1 : 0;
    const int slo   = ylo / SEG;

    float a00 = 0.f, a01 = 0.f, a02 = 0.f, a03 = 0.f;
    float a10 = 0.f, a11 = 0.f, a12 = 0.f, a13 = 0.f;

    #pragma unroll
    for (int c = 0; c < CC; ++c) {
        float4 w4 = *(const float4*)(Wgt + ((size_t)c * HH + y) * WW + x0);
        F4 Vj0 = windowV(PH, Off, c * LL + l0,     yhi, shi, haslo, ylo, slo, x0);
        F4 Vj1 = windowV(PH, Off, c * LL + l0 + 1, yhi, shi, haslo, ylo, slo, x0);
        a00 += w4.x * Vj0.v0; a01 += w4.y * Vj0.v1;
        a02 += w4.z * Vj0.v2; a03 += w4.w * Vj0.v3;
        a10 += w4.x * Vj1.v0; a11 += w4.y * Vj1.v1;
        a12 += w4.z * Vj1.v2; a13 += w4.w * Vj1.v3;
    }
    float4 o0; o0.x = a00; o0.y = a01; o0.z = a02; o0.w = a03;
    float4 o1; o1.x = a10; o1.y = a11; o1.z = a12; o1.w = a13;
    *(float4*)(out + ((size_t)(l0 + 0) * HH + y) * WW + x0) = o0;
    *(float4*)(out + ((size_t)(l0 + 1) * HH + y) * WW + x0) = o1;
}

// =====================================================================

extern "C" void kernel_launch(void* const* d_in, const int* in_sizes, int n_in,
                              void* d_out, int out_size, void* d_ws, size_t ws_size,
                              hipStream_t stream) {
    const float* ca = (const float*)d_in[0];   // (8,1024,1024)
    const float* nn = (const float*)d_in[1];   // (1,8,1024,1024)
    float* out = (float*)d_out;                // (8,1024,1024)

    // workspace: PH bf16 [72][H][W] (151 MB) | SegT f32 (19 MB)
    //            | Off f32 (19 MB) | Wgt f32 [8][H][W] (33.5 MB) => 222 MB
    u16*   PH   = (u16*)d_ws;
    float* SegT = (float*)((char*)d_ws + (size_t)NPL * HH * WW * sizeof(u16));
    float* Off  = SegT + (size_t)NPL * NSEG * WW;
    float* Wgt  = Off  + (size_t)NPL * NSEG * WW;

    hprefix10<<<dim3(NBLK), 128, 0, stream>>>(ca, nn, PH, SegT);
    segscan<<<dim3(NPL, 4), 256, 0, stream>>>(SegT, Off);
    wgtk<<<dim3(HH), 256, 0, stream>>>(ca, PH, Off, Wgt);
    vcombine3<<<dim3(HH * 4), 256, 0, stream>>>(Wgt, PH, Off, out);
}